// Round 6
// baseline (416.829 us; speedup 1.0000x reference)
//
#include <hip/hip_runtime.h>

// LSTMP via MFMA, fp32 I/O, f16 compute, fp32 accumulate.
// B=4096, T=512, IN=4, HID=64, PROJ=52.
// Round-6: TWO independent blocks per CU (512 blocks x 256 thr, 8 batch/block,
// launch_bounds(256,2)) so the two waves on each SIMD have INDEPENDENT barriers
// and can run anti-phase: one block's trans-heavy activation overlaps the other
// block's MFMA phases (R5 showed same-barrier waves serialize phase-by-phase).
//  - wave w owns hid [16w,16w+16) full gate tiles (R4 mapping); batch cols 0-7
//    valid, cols 8-15 idle in MFMA only (MFMA N-redundancy is cheap).
//  - EXACT activation partition (trans floor = 40 instr/SIMD preserved):
//    after gates, 8 ds_bpermute + selects move rows r={2,3} of batch c to
//    lanes col=c+8 -> every lane owns exactly 2 (hid,batch) units.
//  - d exchange via LDS rows 0-7 (rows 8-15 zeroed once), double-buffered,
//    ONE barrier/step; projection redundant per wave with permuted A-frags;
//    h' rebuilt in-register (C layout == gate B-frag layout).
//  - log2e folded into weights (i,f,o xL; g x2L; c kept as c'=2L*c).
// Numerics identical to rounds 4/5 -> absmax ~9.8e-4.

#define T_STEPS 512
#define HID 64
#define NPROJ 52
#define NBATCH 8            // batches per block
#define ROWB 136            // LDS d-row stride bytes (128B data + 8B pad)
#define LOG2E 1.44269504088896340736f

typedef _Float16 half8 __attribute__((ext_vector_type(8)));
typedef float f32x4 __attribute__((ext_vector_type(4)));

__device__ __forceinline__ float exp2_f(float x) {
#if __has_builtin(__builtin_amdgcn_exp2f)
    return __builtin_amdgcn_exp2f(x);
#else
    return exp2f(x);
#endif
}
__device__ __forceinline__ float rcp_f(float x) {
    return __builtin_amdgcn_rcpf(x);
}
__device__ __forceinline__ float bperm_f(int addrB, float v) {
    return __int_as_float(__builtin_amdgcn_ds_bpermute(addrB, __float_as_int(v)));
}

__global__ __launch_bounds__(256, 2)
void lstmp_kernel(const float* __restrict__ x,      // [4096][512][4]
                  const float* __restrict__ Wih,    // [256][4]
                  const float* __restrict__ Whh,    // [256][52]
                  const float* __restrict__ bih,    // [256]
                  const float* __restrict__ bhh,    // [256]
                  const float* __restrict__ Whr,    // [52][64]
                  float* __restrict__ out)          // [4096][52]
{
    __shared__ unsigned long long dlds[2 * 16 * ROWB / 8]; // double-buffered d, 16 rows each

    const int lane = threadIdx.x & 63;
    const int wave = threadIdx.x >> 6;           // 0..3
    const int quad = lane >> 4;
    const int col  = lane & 15;
    const bool lowhalf = (col < 8);
    const int srcB = (lane & ~8) << 2;           // bpermute byte addr: lane with col bit3 cleared

    // ---- gate A-fragments, log2e-folded (one-time; full 16 rows per tile) ----
    half8 aG[4][2];
    const int hid = wave * 16 + col;
#pragma unroll
    for (int g = 0; g < 4; ++g) {
        const float scale = (g == 2) ? (2.0f * LOG2E) : LOG2E;  // g-gate: tanh needs exp(2x)
        const int row = g * HID + hid;
#pragma unroll
        for (int ch = 0; ch < 2; ++ch) {
#pragma unroll
            for (int j = 0; j < 8; ++j) {
                const int k = ch * 32 + quad * 8 + j;
                float v;
                if (k < NPROJ)      v = Whh[row * NPROJ + k];
                else if (k < 56)    v = Wih[row * 4 + (k - NPROJ)];
                else if (k == 56)   v = bih[row] + bhh[row];
                else                v = 0.0f;
                aG[g][ch][j] = (_Float16)(v * scale);
            }
        }
    }

    // ---- proj A-fragments, row-permuted tiles (one-time) ----
    half8 aP[4][2];
#pragma unroll
    for (int tt = 0; tt < 4; ++tt) {
        const int p = ((tt >> 1) * 32) + ((col >> 2) * 8) + ((tt & 1) * 4) + (col & 3);
#pragma unroll
        for (int ch = 0; ch < 2; ++ch) {
#pragma unroll
            for (int j = 0; j < 8; ++j) {
                const int k = ch * 32 + quad * 8 + j;
                aP[tt][ch][j] = (_Float16)((p < NPROJ) ? Whr[p * HID + k] : 0.0f);
            }
        }
    }

    // ---- zero entire d LDS once (rows 8-15 stay zero forever) ----
    {
        unsigned* ldw = (unsigned*)dlds;
        const int tot = (int)(sizeof(dlds) / 4);
        for (int i = threadIdx.x; i < tot; i += 256) ldw[i] = 0u;
    }

    // ---- x registers (batch = col & 7; redundant across waves/halves, L1-served) ----
    const float4* xp = (const float4*)x + (size_t)blockIdx.x * NBATCH * T_STEPS;
    const float4 x0 = xp[(size_t)(col & 7) * T_STEPS + 0];
    float4 xv = xp[(size_t)(col & 7) * T_STEPS + 1];   // holds x(t+1) during iteration t

    // ---- initial gate B-frags (t=0): h=0, x(0), bias-one ----
    half8 b0, b1;
#pragma unroll
    for (int j = 0; j < 8; ++j) { b0[j] = (_Float16)0.0f; b1[j] = (_Float16)0.0f; }
    if (quad == 2) {             // k=52..55 = x (cols>=8 get batch c-8's x: harmless)
        b1[4] = (_Float16)x0.x; b1[5] = (_Float16)x0.y;
        b1[6] = (_Float16)x0.z; b1[7] = (_Float16)x0.w;
    }
    if (quad == 3) {             // k=56 = 1.0 (bias column)
        b1[0] = (_Float16)1.0f;
    }

    float cacc[2] = {0.0f, 0.0f};   // c' = 2L*c for this lane's 2 owned units
    f32x4 hp[4];                    // proj C-results (permuted layout)

    // d write: hid = 16w + quad*4 + (lowhalf?0:2) + {0,1}, row = col&7
    const int dwoff = (col & 7) * ROWB + (16 * wave + quad * 4 + (lowhalf ? 0 : 2)) * 2;
    const int drbase = col * ROWB + quad * 16;   // d read base (+ch*64); rows>=8 read zeros

    __syncthreads();

    // seed anti-phase between the two co-resident blocks
    if (blockIdx.x & 1) __builtin_amdgcn_s_sleep(16);

#pragma unroll 1
    for (int t = 0; t < T_STEPS; ++t) {
        // ---- gates: 8 MFMA, K=64 ----
        f32x4 ai = {0.f,0.f,0.f,0.f}, af_ = {0.f,0.f,0.f,0.f};
        f32x4 ag_ = {0.f,0.f,0.f,0.f}, ao_ = {0.f,0.f,0.f,0.f};
        ai  = __builtin_amdgcn_mfma_f32_16x16x32_f16(aG[0][0], b0, ai,  0, 0, 0);
        af_ = __builtin_amdgcn_mfma_f32_16x16x32_f16(aG[1][0], b0, af_, 0, 0, 0);
        ag_ = __builtin_amdgcn_mfma_f32_16x16x32_f16(aG[2][0], b0, ag_, 0, 0, 0);
        ao_ = __builtin_amdgcn_mfma_f32_16x16x32_f16(aG[3][0], b0, ao_, 0, 0, 0);
        ai  = __builtin_amdgcn_mfma_f32_16x16x32_f16(aG[0][1], b1, ai,  0, 0, 0);
        af_ = __builtin_amdgcn_mfma_f32_16x16x32_f16(aG[1][1], b1, af_, 0, 0, 0);
        ag_ = __builtin_amdgcn_mfma_f32_16x16x32_f16(aG[2][1], b1, ag_, 0, 0, 0);
        ao_ = __builtin_amdgcn_mfma_f32_16x16x32_f16(aG[3][1], b1, ao_, 0, 0, 0);

        // ---- redistribute: lanes col>=8 take rows r={2,3} of batch col-8 ----
        // (8 bpermute + 8 selects; every lane then owns exactly 2 units)
        float yi0, yi1, yf0, yf1, yg0, yg1, yo0, yo1;
        {
            const float ti2 = bperm_f(srcB, ai[2]),  ti3 = bperm_f(srcB, ai[3]);
            const float tf2 = bperm_f(srcB, af_[2]), tf3 = bperm_f(srcB, af_[3]);
            const float tg2 = bperm_f(srcB, ag_[2]), tg3 = bperm_f(srcB, ag_[3]);
            const float to2 = bperm_f(srcB, ao_[2]), to3 = bperm_f(srcB, ao_[3]);
            yi0 = lowhalf ? ai[0]  : ti2;  yi1 = lowhalf ? ai[1]  : ti3;
            yf0 = lowhalf ? af_[0] : tf2;  yf1 = lowhalf ? af_[1] : tf3;
            yg0 = lowhalf ? ag_[0] : tg2;  yg1 = lowhalf ? ag_[1] : tg3;
            yo0 = lowhalf ? ao_[0] : to2;  yo1 = lowhalf ? ao_[1] : to3;
        }

        // ---- activations for the 2 owned units (20 trans/wave) ----
        char* dbuf = (char*)dlds + (t & 1) * (16 * ROWB);
        union { _Float16 h[2]; unsigned w; } du;
        {
            const float yi[2] = {yi0, yi1}, yf[2] = {yf0, yf1};
            const float yg[2] = {yg0, yg1}, yo[2] = {yo0, yo1};
#pragma unroll
            for (int u = 0; u < 2; ++u) {
                const float iv = rcp_f(1.0f + exp2_f(-yi[u]));                   // sigmoid
                const float fv = rcp_f(1.0f + exp2_f(-yf[u]));
                const float ov = rcp_f(1.0f + exp2_f(-yo[u]));
                const float gs = fmaf(-4.0f * LOG2E, rcp_f(1.0f + exp2_f(yg[u])),
                                      2.0f * LOG2E);                             // 2L*tanh(g)
                const float cn = fmaf(fv, cacc[u], iv * gs);                     // c' = 2L*c
                cacc[u] = cn;
                const float th = fmaf(-2.0f, rcp_f(1.0f + exp2_f(cn)), 1.0f);    // tanh(c)
                du.h[u] = (_Float16)(ov * th);                                   // RTNE
            }
        }
        *(unsigned*)(dbuf + dwoff) = du.w;
        __syncthreads();                     // the ONLY barrier per step

        // ---- d B-frags from LDS (rows >= 8 give zeros -> proj cols 8-15 = 0) ----
        half8 bd0, bd1;
        {
            const char* p0 = dbuf + drbase;
            union { unsigned long long q[2]; half8 h; } u0, u1;
            u0.q[0] = *(const unsigned long long*)(p0);
            u0.q[1] = *(const unsigned long long*)(p0 + 8);
            u1.q[0] = *(const unsigned long long*)(p0 + 64);
            u1.q[1] = *(const unsigned long long*)(p0 + 72);
            bd0 = u0.h; bd1 = u1.h;
        }

        // ---- projection: 8 MFMA, redundant per wave, permuted tiles ----
#pragma unroll
        for (int tt = 0; tt < 4; ++tt) {
            f32x4 acc = {0.f, 0.f, 0.f, 0.f};
            acc = __builtin_amdgcn_mfma_f32_16x16x32_f16(aP[tt][0], bd0, acc, 0, 0, 0);
            acc = __builtin_amdgcn_mfma_f32_16x16x32_f16(aP[tt][1], bd1, acc, 0, 0, 0);
            hp[tt] = acc;
        }

        // ---- build next-step gate B-frags in-register (h' = permuted C layout) ----
#pragma unroll
        for (int j = 0; j < 4; ++j) {
            b0[j]     = (_Float16)hp[0][j];   // k = quad*8 + j
            b0[4 + j] = (_Float16)hp[1][j];   // k = quad*8 + 4 + j
            b1[j]     = (_Float16)hp[2][j];   // k = 32 + quad*8 + j
            b1[4 + j] = (_Float16)hp[3][j];   // k = 32 + quad*8 + 4 + j
        }
        if (quad == 2) {                      // k=52..55 <- x(t+1)
            b1[4] = (_Float16)xv.x; b1[5] = (_Float16)xv.y;
            b1[6] = (_Float16)xv.z; b1[7] = (_Float16)xv.w;
        }
        if (quad == 3) {                      // k=56 <- 1.0
            b1[0] = (_Float16)1.0f;
        }

        // prefetch x(t+2)
        const int tn = (t + 2 < T_STEPS) ? (t + 2) : (T_STEPS - 1);
        xv = xp[(size_t)(col & 7) * T_STEPS + tn];
    }

    // ---- epilogue: wave 0, cols 0-7 hold valid h_T (fp32, permuted C layout) ----
    if (wave == 0 && lowhalf) {
        const size_t bg = (size_t)blockIdx.x * NBATCH + col;
        float* o = out + bg * NPROJ;
#pragma unroll
        for (int tt = 0; tt < 4; ++tt) {
            const int pb = ((tt >> 1) * 32) + (quad * 8) + ((tt & 1) * 4);
#pragma unroll
            for (int r = 0; r < 4; ++r) {
                const int p = pb + r;
                if (p < NPROJ) o[p] = hp[tt][r];
            }
        }
    }
}

extern "C" void kernel_launch(void* const* d_in, const int* in_sizes, int n_in,
                              void* d_out, int out_size, void* d_ws, size_t ws_size,
                              hipStream_t stream) {
    const float* x   = (const float*)d_in[0];
    const float* Wih = (const float*)d_in[1];
    const float* Whh = (const float*)d_in[2];
    const float* bih = (const float*)d_in[3];
    const float* bhh = (const float*)d_in[4];
    const float* Whr = (const float*)d_in[5];
    float* out = (float*)d_out;

    dim3 grid(4096 / NBATCH);     // 512 blocks -> 2 independent blocks per CU
    dim3 block(256);              // 4 waves
    lstmp_kernel<<<grid, block, 0, stream>>>(x, Wih, Whh, bih, bhh, Whr, out);
}

// Round 7
// 310.633 us; speedup vs baseline: 1.3419x; 1.3419x over previous
//
#include <hip/hip_runtime.h>

// LSTMP via MFMA, fp32 I/O, f16 compute, fp32 accumulate.
// B=4096, T=512, IN=4, HID=64, PROJ=52. Grid 256 x 256thr (4 waves), 16 batch/block.
//
// Round-7: projection folded into the recurrence algebraically.
//   gates = Whh*h + Wih*x + b,  h = Whr*d  ==>  gates = (Whh*Whr)*d + Wih*x + b
// M = Whh@Whr (256x64) precomputed per block in fp32 (~3us one-time), stored as
// log2e-folded f16 A-frags. Recurrent state = d (f16, LDS B-frag layout) + c
// (fp32 per-lane). Per step per wave: 4 xb-MFMA (K=32, [Wih|b]@[x;1]) seeding
// the accumulators + 8 M-MFMA (K=64) + activations + d write. ONE barrier.
// No projection in the loop; h = Whr@d computed once in the epilogue.
// d exchange double-buffered in LDS (ROWB=136 pad, measured 0 conflicts, R4).
// log2e folded into M/Wih/b (i,f,o rows xL; g rows x2L; c kept as c'=2L*c);
// sigmoid/tanh via raw v_exp_f32 (exp2) + v_rcp_f32. d converts stay RTNE.

#define T_STEPS 512
#define HID 64
#define NPROJ 52
#define NBATCH 16
#define ROWB 136
#define DBYTES (NBATCH * ROWB)
#define LOG2E 1.44269504088896340736f

typedef _Float16 half8 __attribute__((ext_vector_type(8)));
typedef float f32x4 __attribute__((ext_vector_type(4)));

__device__ __forceinline__ float exp2_f(float x) {
#if __has_builtin(__builtin_amdgcn_exp2f)
    return __builtin_amdgcn_exp2f(x);
#else
    return exp2f(x);
#endif
}
__device__ __forceinline__ float rcp_f(float x) {
    return __builtin_amdgcn_rcpf(x);
}

__global__ __launch_bounds__(256, 1)
void lstmp_kernel(const float* __restrict__ x,      // [4096][512][4]
                  const float* __restrict__ Wih,    // [256][4]
                  const float* __restrict__ Whh,    // [256][52]
                  const float* __restrict__ bih,    // [256]
                  const float* __restrict__ bhh,    // [256]
                  const float* __restrict__ Whr,    // [52][64]
                  float* __restrict__ out)          // [4096][52]
{
    __shared__ char dlds[2 * DBYTES];   // double-buffered d, [16 batch][136B]

    const int lane = threadIdx.x & 63;
    const int wave = threadIdx.x >> 6;   // 0..3
    const int quad = lane >> 4;
    const int col  = lane & 15;          // batch (B/C col), row-in-tile (A)

    // ---- zero LDS (t=0 reads buffer 0 as d(-1)=0) ----
    {
        unsigned* ldw = (unsigned*)dlds;
        const int tot = (int)(2 * DBYTES / 4);
        for (int i = threadIdx.x; i < tot; i += 256) ldw[i] = 0u;
    }

    // ---- one-time: M = Whh @ Whr for this wave's 4 gate tiles (fp32) ----
    // A-frag slot (g, kk=ch*8+j) -> gate row g*64+hid, k = ch*32 + quad*8 + j.
    const int hid = wave * 16 + col;
    float macc[4][16];
#pragma unroll
    for (int g = 0; g < 4; ++g)
#pragma unroll
        for (int kk = 0; kk < 16; ++kk) macc[g][kk] = 0.0f;

    for (int p = 0; p < NPROJ; ++p) {
        float wv[4];
#pragma unroll
        for (int g = 0; g < 4; ++g) wv[g] = Whh[(g * HID + hid) * NPROJ + p];
        const float* wr = Whr + p * HID + quad * 8;     // 16B aligned
        const float4 r0 = *(const float4*)(wr);
        const float4 r1 = *(const float4*)(wr + 4);
        const float4 r2 = *(const float4*)(wr + 32);
        const float4 r3 = *(const float4*)(wr + 36);
        const float rk[16] = {r0.x, r0.y, r0.z, r0.w, r1.x, r1.y, r1.z, r1.w,
                              r2.x, r2.y, r2.z, r2.w, r3.x, r3.y, r3.z, r3.w};
#pragma unroll
        for (int g = 0; g < 4; ++g)
#pragma unroll
            for (int kk = 0; kk < 16; ++kk) macc[g][kk] = fmaf(wv[g], rk[kk], macc[g][kk]);
    }

    // ---- fold scale, convert to f16 A-frags ----
    half8 aM[4][2];    // M-part, K=64 (2 chunks)
    half8 aXB[4];      // [Wih | bias] part, K=32 (k<4 = x, k==4 = 1-column)
#pragma unroll
    for (int g = 0; g < 4; ++g) {
        const float scale = (g == 2) ? (2.0f * LOG2E) : LOG2E;
#pragma unroll
        for (int ch = 0; ch < 2; ++ch)
#pragma unroll
            for (int j = 0; j < 8; ++j)
                aM[g][ch][j] = (_Float16)(macc[g][ch * 8 + j] * scale);
        const int row = g * HID + hid;
#pragma unroll
        for (int j = 0; j < 8; ++j) {
            const int k = quad * 8 + j;
            float v = 0.0f;
            if (k < 4)       v = Wih[row * 4 + k];
            else if (k == 4) v = bih[row] + bhh[row];
            aXB[g][j] = (_Float16)(v * scale);
        }
    }

    // ---- x stream (per-lane batch = col; uniform across quads/waves, L1-served) ----
    const float4* xp = (const float4*)x + (size_t)blockIdx.x * NBATCH * T_STEPS;
    const float4 xq0 = xp[(size_t)col * T_STEPS + 0];
    float4 xv = xp[(size_t)col * T_STEPS + 1];          // x(t+1) during iter t

    half8 bx;                                           // B-frag of [x(t);1;0..]
#pragma unroll
    for (int j = 0; j < 8; ++j) bx[j] = (_Float16)0.0f;
    if (quad == 0) {
        bx[0] = (_Float16)xq0.x; bx[1] = (_Float16)xq0.y;
        bx[2] = (_Float16)xq0.z; bx[3] = (_Float16)xq0.w;
        bx[4] = (_Float16)1.0f;
    }

    float cacc[4] = {0.0f, 0.0f, 0.0f, 0.0f};           // c' = 2L*c, hid = 16w+quad*4+r

    const int dwoff  = col * ROWB + wave * 32 + quad * 8;  // d write (b64)
    const int drbase = col * ROWB + quad * 16;             // d read base (+ch*64)

    __syncthreads();   // LDS zero visible

#pragma unroll 1
    for (int t = 0; t < T_STEPS; ++t) {
        const char* rbuf = dlds + (t & 1) * DBYTES;
        char* wbuf = dlds + ((t + 1) & 1) * DBYTES;

        // seed accumulators with x+bias contribution (independent of barrier/d)
        f32x4 ai = {0.f,0.f,0.f,0.f}, af_ = {0.f,0.f,0.f,0.f};
        f32x4 ag_ = {0.f,0.f,0.f,0.f}, ao_ = {0.f,0.f,0.f,0.f};
        ai  = __builtin_amdgcn_mfma_f32_16x16x32_f16(aXB[0], bx, ai,  0, 0, 0);
        af_ = __builtin_amdgcn_mfma_f32_16x16x32_f16(aXB[1], bx, af_, 0, 0, 0);
        ag_ = __builtin_amdgcn_mfma_f32_16x16x32_f16(aXB[2], bx, ag_, 0, 0, 0);
        ao_ = __builtin_amdgcn_mfma_f32_16x16x32_f16(aXB[3], bx, ao_, 0, 0, 0);

        // d(t-1) B-frags from LDS
        half8 bd0, bd1;
        {
            const char* p0 = rbuf + drbase;
            union { unsigned long long q[2]; half8 h; } u0, u1;
            u0.q[0] = *(const unsigned long long*)(p0);
            u0.q[1] = *(const unsigned long long*)(p0 + 8);
            u1.q[0] = *(const unsigned long long*)(p0 + 64);
            u1.q[1] = *(const unsigned long long*)(p0 + 72);
            bd0 = u0.h; bd1 = u1.h;
        }

        // build next step's x B-frag; prefetch x(t+2) early (drains before barrier)
        half8 bxn;
#pragma unroll
        for (int j = 0; j < 8; ++j) bxn[j] = (_Float16)0.0f;
        if (quad == 0) {
            bxn[0] = (_Float16)xv.x; bxn[1] = (_Float16)xv.y;
            bxn[2] = (_Float16)xv.z; bxn[3] = (_Float16)xv.w;
            bxn[4] = (_Float16)1.0f;
        }
        const int tn = (t + 2 < T_STEPS) ? (t + 2) : (T_STEPS - 1);
        const float4 xnew = xp[(size_t)col * T_STEPS + tn];

        // gates += M @ d : 8 MFMA, K=64
        ai  = __builtin_amdgcn_mfma_f32_16x16x32_f16(aM[0][0], bd0, ai,  0, 0, 0);
        af_ = __builtin_amdgcn_mfma_f32_16x16x32_f16(aM[1][0], bd0, af_, 0, 0, 0);
        ag_ = __builtin_amdgcn_mfma_f32_16x16x32_f16(aM[2][0], bd0, ag_, 0, 0, 0);
        ao_ = __builtin_amdgcn_mfma_f32_16x16x32_f16(aM[3][0], bd0, ao_, 0, 0, 0);
        ai  = __builtin_amdgcn_mfma_f32_16x16x32_f16(aM[0][1], bd1, ai,  0, 0, 0);
        af_ = __builtin_amdgcn_mfma_f32_16x16x32_f16(aM[1][1], bd1, af_, 0, 0, 0);
        ag_ = __builtin_amdgcn_mfma_f32_16x16x32_f16(aM[2][1], bd1, ag_, 0, 0, 0);
        ao_ = __builtin_amdgcn_mfma_f32_16x16x32_f16(aM[3][1], bd1, ao_, 0, 0, 0);

        // activations + cell update (per-lane; hid = 16w + quad*4 + r); d -> RTNE f16
        union { _Float16 h[4]; unsigned long long q; } du;
#pragma unroll
        for (int r = 0; r < 4; ++r) {
            const float iv = rcp_f(1.0f + exp2_f(-ai[r]));                       // sigmoid
            const float fv = rcp_f(1.0f + exp2_f(-af_[r]));
            const float ov = rcp_f(1.0f + exp2_f(-ao_[r]));
            const float gs = fmaf(-4.0f * LOG2E, rcp_f(1.0f + exp2_f(ag_[r])),
                                  2.0f * LOG2E);                                 // 2L*tanh(g)
            const float cn = fmaf(fv, cacc[r], iv * gs);                         // c' = 2L*c
            cacc[r] = cn;
            const float th = fmaf(-2.0f, rcp_f(1.0f + exp2_f(cn)), 1.0f);        // tanh(c)
            du.h[r] = (_Float16)(ov * th);                                       // RTNE
        }
        *(unsigned long long*)(wbuf + dwoff) = du.q;

        bx = bxn;
        xv = xnew;
        __syncthreads();   // the ONLY barrier per step
    }

    // ---- epilogue: h_T = Whr @ d(T-1); d(T-1) is in buffer (T&1)==0 ----
    half8 aP[2];
    const int prow = wave * 16 + col;
#pragma unroll
    for (int ch = 0; ch < 2; ++ch)
#pragma unroll
        for (int j = 0; j < 8; ++j) {
            const int k = ch * 32 + quad * 8 + j;
            aP[ch][j] = (_Float16)((prow < NPROJ) ? Whr[prow * HID + k] : 0.0f);
        }

    half8 bd0, bd1;
    {
        const char* p0 = dlds + 0 * DBYTES + drbase;
        union { unsigned long long q[2]; half8 h; } u0, u1;
        u0.q[0] = *(const unsigned long long*)(p0);
        u0.q[1] = *(const unsigned long long*)(p0 + 8);
        u1.q[0] = *(const unsigned long long*)(p0 + 64);
        u1.q[1] = *(const unsigned long long*)(p0 + 72);
        bd0 = u0.h; bd1 = u1.h;
    }
    f32x4 hf = {0.f, 0.f, 0.f, 0.f};
    hf = __builtin_amdgcn_mfma_f32_16x16x32_f16(aP[0], bd0, hf, 0, 0, 0);
    hf = __builtin_amdgcn_mfma_f32_16x16x32_f16(aP[1], bd1, hf, 0, 0, 0);

    // store: p = wave*16 + quad*4 + r, batch = col  (wave 3: only quad 0 valid)
    const size_t bg = (size_t)blockIdx.x * NBATCH + col;
    float* o = out + bg * NPROJ;
    const int p0 = wave * 16 + quad * 4;
#pragma unroll
    for (int r = 0; r < 4; ++r) {
        const int p = p0 + r;
        if (p < NPROJ) o[p] = hf[r];
    }
}

extern "C" void kernel_launch(void* const* d_in, const int* in_sizes, int n_in,
                              void* d_out, int out_size, void* d_ws, size_t ws_size,
                              hipStream_t stream) {
    const float* x   = (const float*)d_in[0];
    const float* Wih = (const float*)d_in[1];
    const float* Whh = (const float*)d_in[2];
    const float* bih = (const float*)d_in[3];
    const float* bhh = (const float*)d_in[4];
    const float* Whr = (const float*)d_in[5];
    float* out = (float*)d_out;

    dim3 grid(4096 / NBATCH);   // 256 blocks, 1 per CU
    dim3 block(256);            // 4 waves, 1 wave/SIMD
    lstmp_kernel<<<grid, block, 0, stream>>>(x, Wih, Whh, bih, bhh, Whr, out);
}